// Round 1
// baseline (293.736 us; speedup 1.0000x reference)
//
#include <hip/hip_runtime.h>
#include <hip/hip_bf16.h>
#include <stdint.h>

#define M_TOT 16384     // B*P = 64*256
#define DM 768
#define NKT 24          // K / 32

typedef __attribute__((ext_vector_type(4))) float f32x4;
typedef __attribute__((ext_vector_type(8))) short short8;
typedef __attribute__((ext_vector_type(4))) unsigned short ushort4v;

__device__ __forceinline__ unsigned short f2bf(float f) {
    union { float f; unsigned u; } v; v.f = f;
    unsigned r = v.u + 0x7fffu + ((v.u >> 16) & 1u);
    return (unsigned short)(r >> 16);
}
__device__ __forceinline__ float bf2f(unsigned short h) {
    union { unsigned u; float f; } v; v.u = ((unsigned)h) << 16;
    return v.f;
}

__device__ __forceinline__ void gload_lds16(const unsigned short* g, unsigned short* l) {
    __builtin_amdgcn_global_load_lds(
        (const __attribute__((address_space(1))) void*)g,
        (__attribute__((address_space(3))) void*)l, 16, 0, 0);
}

// ---------------- weight fp32 -> bf16 ----------------
__global__ __launch_bounds__(256)
void cvt_bf16(const float* __restrict__ src, unsigned short* __restrict__ dst, int n4)
{
    int i = blockIdx.x * 256 + threadIdx.x;
    if (i >= n4) return;
    f32x4 v = ((const f32x4*)src)[i];
    ushort4v o;
    o.x = f2bf(v.x); o.y = f2bf(v.y); o.z = f2bf(v.z); o.w = f2bf(v.w);
    ((ushort4v*)dst)[i] = o;
}

// ---------------- inverse permutation ----------------
__global__ void build_invperm(const int* __restrict__ perm, int* __restrict__ invp)
{
    int i = blockIdx.x * 256 + threadIdx.x;   // 16384
    int b = i >> 8;
    invp[(b << 8) + perm[i]] = i & 255;
}

// ---------------- im2col: x[B,3,256,256] -> patches[16384,768] bf16 ----------------
__global__ __launch_bounds__(256)
void im2col(const float* __restrict__ x, unsigned short* __restrict__ patches)
{
    int t = blockIdx.x * 256 + threadIdx.x;     // 3,145,728 total (4 floats each)
    int bp = t / 192;
    int q  = t - bp * 192;        // quad within the 768-wide row
    int c   = q >> 6;             // channel 0..2
    int kh  = (q >> 2) & 15;
    int kw0 = (q & 3) << 2;
    int b = bp >> 8, p = bp & 255;
    int ph = p >> 4, pw = p & 15;
    const float* src = x + ((((size_t)b * 3 + c) * 256 + ph * 16 + kh) * 256 + pw * 16 + kw0);
    f32x4 v = *(const f32x4*)src;
    ushort4v o;
    o.x = f2bf(v.x); o.y = f2bf(v.y); o.z = f2bf(v.z); o.w = f2bf(v.w);
    *(ushort4v*)(patches + (size_t)bp * DM + (q << 2)) = o;
}

// ---------------- GEMM: out[M,768] = A[M,768] * Bw[768,768]^T + bias ----------------
// EPI 0: relu -> bf16 ; EPI 1: -> bf16 (pre-BN) ; EPI 2: perm-scatter -> f32
template<int EPI>
__global__ __launch_bounds__(256)
void gemm_bt(const unsigned short* __restrict__ A,
             const unsigned short* __restrict__ Bw,
             const float* __restrict__ bias,
             void* __restrict__ outp,
             const int* __restrict__ invp)
{
    __shared__ unsigned short Asm[2][128 * 32];
    __shared__ unsigned short Bsm[2][128 * 32];

    const int tid  = threadIdx.x;
    const int wave = tid >> 6;
    const int lane = tid & 63;
    const int wr = wave >> 1, wc = wave & 1;
    const int tileN = blockIdx.x;   // 0..5
    const int tileM = blockIdx.y;   // 0..127

    // staging: per wave-instr (i,w): 16 rows x 32 cols, lane -> row (l>>2), colbytes (l&3)*16
    const int stRow = wave * 16 + (lane >> 2);
    const int stCol = (lane & 3) * 8;
    const unsigned short* gA = A  + (size_t)(tileM * 128 + stRow) * DM + stCol;
    const unsigned short* gB = Bw + (size_t)(tileN * 128 + stRow) * DM + stCol;
    const int ldsOff = wave * 512;   // shorts; + i*2048

    f32x4 acc[4][4] = {};

    const int frow = lane & 15;
    const int fk   = (lane >> 4) * 8;

    auto STAGE = [&](int bi, int kk) {
        #pragma unroll
        for (int i = 0; i < 2; ++i) {
            gload_lds16(gA + i * (64 * DM) + kk * 32, &Asm[bi][ldsOff + i * 2048]);
            gload_lds16(gB + i * (64 * DM) + kk * 32, &Bsm[bi][ldsOff + i * 2048]);
        }
    };

    STAGE(0, 0);
    __syncthreads();
    int buf = 0;
    for (int kk = 0; kk < NKT; ++kk) {
        if (kk + 1 < NKT) STAGE(buf ^ 1, kk + 1);
        short8 a[4], bfr[4];
        #pragma unroll
        for (int i = 0; i < 4; ++i)
            a[i] = *(const short8*)&Asm[buf][(wr * 64 + i * 16 + frow) * 32 + fk];
        #pragma unroll
        for (int j = 0; j < 4; ++j)
            bfr[j] = *(const short8*)&Bsm[buf][(wc * 64 + j * 16 + frow) * 32 + fk];
        #pragma unroll
        for (int i = 0; i < 4; ++i)
            #pragma unroll
            for (int j = 0; j < 4; ++j)
                acc[i][j] = __builtin_amdgcn_mfma_f32_16x16x32_bf16(a[i], bfr[j], acc[i][j], 0, 0, 0);
        __syncthreads();
        buf ^= 1;
    }

    const int baseM = tileM * 128 + wr * 64;
    const int baseN = tileN * 128 + wc * 64;
    const int crow = (lane >> 4) * 4;
    const int ccol = lane & 15;

    float bv[4];
    #pragma unroll
    for (int j = 0; j < 4; ++j) bv[j] = bias[baseN + j * 16 + ccol];

    if (EPI == 2) {
        float* O = (float*)outp;
        #pragma unroll
        for (int i = 0; i < 4; ++i) {
            #pragma unroll
            for (int r = 0; r < 4; ++r) {
                int m = baseM + i * 16 + crow + r;
                int mo = (m & ~255) | invp[m];
                float* orow = O + (size_t)mo * DM + baseN + ccol;
                #pragma unroll
                for (int j = 0; j < 4; ++j)
                    orow[j * 16] = acc[i][j][r] + bv[j];
            }
        }
    } else {
        unsigned short* O = (unsigned short*)outp;
        #pragma unroll
        for (int i = 0; i < 4; ++i) {
            #pragma unroll
            for (int r = 0; r < 4; ++r) {
                int m = baseM + i * 16 + crow + r;
                unsigned short* orow = O + (size_t)m * DM + baseN + ccol;
                #pragma unroll
                for (int j = 0; j < 4; ++j) {
                    float v = acc[i][j][r] + bv[j];
                    if (EPI == 0) v = fmaxf(v, 0.0f);
                    orow[j * 16] = f2bf(v);
                }
            }
        }
    }
}

// ---------------- BN stage 1: per-block partial sums over 256 rows ----------------
__global__ __launch_bounds__(256)
void bn_reduce1(const unsigned short* __restrict__ h, float* __restrict__ part)
{
    const int t = threadIdx.x, blk = blockIdx.x;
    const unsigned short* p = h + (size_t)blk * 256 * DM;
    float s0 = 0.f, s1 = 0.f, s2 = 0.f, q0 = 0.f, q1 = 0.f, q2 = 0.f;
    for (int r = 0; r < 256; ++r) {
        float v0 = bf2f(p[r * DM + t]);
        float v1 = bf2f(p[r * DM + t + 256]);
        float v2 = bf2f(p[r * DM + t + 512]);
        s0 += v0; q0 += v0 * v0;
        s1 += v1; q1 += v1 * v1;
        s2 += v2; q2 += v2 * v2;
    }
    float* dst = part + blk * (2 * DM);
    dst[t] = s0; dst[t + 256] = s1; dst[t + 512] = s2;
    dst[DM + t] = q0; dst[DM + t + 256] = q1; dst[DM + t + 512] = q2;
}

// ---------------- BN stage 2: finalize scale/shift ----------------
__global__ void bn_stats(const float* __restrict__ part, const float* __restrict__ gamma,
                         const float* __restrict__ beta, float* __restrict__ ss)
{
    int c = blockIdx.x * 256 + threadIdx.x;   // 768
    float s = 0.f, q = 0.f;
    for (int b = 0; b < 64; ++b) {
        s += part[b * 2 * DM + c];
        q += part[b * 2 * DM + DM + c];
    }
    float mu  = s * (1.0f / 16384.0f);
    float var = q * (1.0f / 16384.0f) - mu * mu;
    float scale = rsqrtf(var + 1e-5f) * gamma[c];
    ss[c] = scale;
    ss[DM + c] = beta[c] - mu * scale;
}

// ---------------- BN apply (+optional pos-emb + second relu) ----------------
template<int POS>
__global__ __launch_bounds__(256)
void bn_apply(const unsigned short* __restrict__ hin, const float* __restrict__ ss,
              const float* __restrict__ pos, unsigned short* __restrict__ hout)
{
    __shared__ float sc[DM], sh[DM];
    const int t = threadIdx.x;
    #pragma unroll
    for (int i = 0; i < 3; ++i) {
        sc[t + i * 256] = ss[t + i * 256];
        sh[t + i * 256] = ss[DM + t + i * 256];
    }
    __syncthreads();

    int g = blockIdx.x * 256 + t;           // 1,572,864 vec8 groups
    int row = g / 96;
    int c0 = (g - row * 96) * 8;
    const short8 v = *(const short8*)(hin + (size_t)row * DM + c0);
    short8 o;
    #pragma unroll
    for (int e = 0; e < 8; ++e) {
        float xv = bf2f((unsigned short)v[e]);
        float y = fmaxf(xv * sc[c0 + e] + sh[c0 + e], 0.0f);
        if (POS) y = fmaxf(y + pos[(row & 255) * DM + c0 + e], 0.0f);
        o[e] = (short)f2bf(y);
    }
    *(short8*)(hout + (size_t)row * DM + c0) = o;
}

extern "C" void kernel_launch(void* const* d_in, const int* in_sizes, int n_in,
                              void* d_out, int out_size, void* d_ws, size_t ws_size,
                              hipStream_t stream)
{
    (void)in_sizes; (void)n_in; (void)out_size; (void)ws_size;

    const float* x       = (const float*)d_in[0];
    const float* conv0_w = (const float*)d_in[1];
    const float* conv0_b = (const float*)d_in[2];
    const float* w1      = (const float*)d_in[3];
    const float* b1      = (const float*)d_in[4];
    const float* gamma   = (const float*)d_in[5];
    const float* beta    = (const float*)d_in[6];
    const float* pos     = (const float*)d_in[7];
    const float* mixer_w = (const float*)d_in[8];
    const float* mixer_b = (const float*)d_in[9];
    const int*   perm    = (const int*)d_in[10];

    // workspace layout (~54 MB)
    unsigned short* actA = (unsigned short*)d_ws;               // 16384*768 bf16
    unsigned short* actB = actA + (size_t)M_TOT * DM;           // 16384*768 bf16
    unsigned short* wA   = actB + (size_t)M_TOT * DM;           // 768*768
    unsigned short* wD   = wA + DM * DM;                        // 3*768*768
    unsigned short* wM   = wD + 3 * DM * DM;                    // 768*768
    float* part = (float*)(wM + DM * DM);                       // 64*2*768
    float* ss   = part + 64 * 2 * DM;                           // 2*768
    int*   invp = (int*)(ss + 2 * DM);                          // 16384

    cvt_bf16<<<576, 256, 0, stream>>>(conv0_w, wA, 147456);
    cvt_bf16<<<1728, 256, 0, stream>>>(w1, wD, 442368);
    cvt_bf16<<<576, 256, 0, stream>>>(mixer_w, wM, 147456);
    build_invperm<<<64, 256, 0, stream>>>(perm, invp);
    im2col<<<12288, 256, 0, stream>>>(x, actA);

    dim3 gg(6, 128);
    // patch embed: relu(patches @ conv0_w^T + b)
    gemm_bt<0><<<gg, 256, 0, stream>>>(actA, wA, conv0_b, actB, nullptr);

    for (int d = 0; d < 3; ++d) {
        gemm_bt<1><<<gg, 256, 0, stream>>>(actB, wD + (size_t)d * DM * DM, b1 + d * DM, actA, nullptr);
        bn_reduce1<<<64, 256, 0, stream>>>(actA, part);
        bn_stats<<<3, 256, 0, stream>>>(part, gamma + d * DM, beta + d * DM, ss);
        if (d < 2) bn_apply<0><<<6144, 256, 0, stream>>>(actA, ss, pos, actB);
        else       bn_apply<1><<<6144, 256, 0, stream>>>(actA, ss, pos, actB);
    }

    // mixer + per-sample permutation scatter to fp32 output
    gemm_bt<2><<<gg, 256, 0, stream>>>(actB, wM, mixer_b, d_out, invp);
}

// Round 2
// 237.765 us; speedup vs baseline: 1.2354x; 1.2354x over previous
//
#include <hip/hip_runtime.h>
#include <hip/hip_bf16.h>
#include <stdint.h>

#define M_TOT 16384     // B*P = 64*256
#define DM 768
#define BM 256
#define BN 192
#define NPAIR 6         // 768 / (64*2)

typedef __attribute__((ext_vector_type(4))) float f32x4;
typedef __attribute__((ext_vector_type(8))) short short8;
typedef __attribute__((ext_vector_type(4))) unsigned short ushort4v;

__device__ __forceinline__ unsigned short f2bf(float f) {
    union { float f; unsigned u; } v; v.f = f;
    unsigned r = v.u + 0x7fffu + ((v.u >> 16) & 1u);
    return (unsigned short)(r >> 16);
}
__device__ __forceinline__ float bf2f(unsigned short h) {
    union { unsigned u; float f; } v; v.u = ((unsigned)h) << 16;
    return v.f;
}

__device__ __forceinline__ void gload_lds16(const unsigned short* g, unsigned short* l) {
    __builtin_amdgcn_global_load_lds(
        (const __attribute__((address_space(1))) void*)g,
        (__attribute__((address_space(3))) void*)l, 16, 0, 0);
}

// ---------------- weight fp32 -> bf16 ----------------
__global__ __launch_bounds__(256)
void cvt_bf16(const float* __restrict__ src, unsigned short* __restrict__ dst, int n4)
{
    int i = blockIdx.x * 256 + threadIdx.x;
    if (i >= n4) return;
    f32x4 v = ((const f32x4*)src)[i];
    ushort4v o;
    o.x = f2bf(v.x); o.y = f2bf(v.y); o.z = f2bf(v.z); o.w = f2bf(v.w);
    ((ushort4v*)dst)[i] = o;
}

// ---------------- inverse permutation ----------------
__global__ void build_invperm(const int* __restrict__ perm, int* __restrict__ invp)
{
    int i = blockIdx.x * 256 + threadIdx.x;   // 16384
    int b = i >> 8;
    invp[(b << 8) + perm[i]] = i & 255;
}

// ---------------- im2col: x[B,3,256,256] -> patches[16384,768] bf16 ----------------
__global__ __launch_bounds__(256)
void im2col(const float* __restrict__ x, unsigned short* __restrict__ patches)
{
    int t = blockIdx.x * 256 + threadIdx.x;     // 3,145,728 total (4 floats each)
    int bp = t / 192;
    int q  = t - bp * 192;        // quad within the 768-wide row
    int c   = q >> 6;             // channel 0..2
    int kh  = (q >> 2) & 15;
    int kw0 = (q & 3) << 2;
    int b = bp >> 8, p = bp & 255;
    int ph = p >> 4, pw = p & 15;
    const float* src = x + ((((size_t)b * 3 + c) * 256 + ph * 16 + kh) * 256 + pw * 16 + kw0);
    f32x4 v = *(const f32x4*)src;
    ushort4v o;
    o.x = f2bf(v.x); o.y = f2bf(v.y); o.z = f2bf(v.z); o.w = f2bf(v.w);
    *(ushort4v*)(patches + (size_t)bp * DM + (q << 2)) = o;
}

// =====================================================================
// 8-phase GEMM: out[M,768] = A[M,768] * Bw[768,768]^T + bias
// BM=256 x BN=192, BK=64, 8 waves (2M x 4N), wave tile 128x48.
// T2 LDS XOR-swizzle, T3/T4 counted vmcnt(3), T5 setprio.
// EPI 0: relu->bf16 ; EPI 1: ->bf16 (pre-BN) ; EPI 2: perm-scatter->f32
// =====================================================================
#define VM3  asm volatile("s_waitcnt vmcnt(3)" ::: "memory");
#define VMSEL if (hn) { asm volatile("s_waitcnt vmcnt(3)" ::: "memory"); } \
              else    { asm volatile("s_waitcnt vmcnt(0)" ::: "memory"); }
#define BARR asm volatile("s_barrier" ::: "memory");
#define NOVM

// phase: [optional B-frag loads] + A-frag loads + stage-issue + MFMA(12) + [vmcnt] + barrier
#define DO_PHASE(BUF, MH, KS, LOADB, VMC, ...)                                   \
  {                                                                              \
    if (LOADB) {                                                                 \
      _Pragma("unroll")                                                          \
      for (int j = 0; j < 3; ++j)                                                \
        breg[j] = *(const short8*)((const char*)Bsh[BUF] +                       \
                  (wc * 48 + j * 16 + frow) * 128 + (((KS) * 64 + fq16) ^ rswz));\
    }                                                                            \
    short8 af[4];                                                                \
    _Pragma("unroll")                                                            \
    for (int i = 0; i < 4; ++i)                                                  \
      af[i] = *(const short8*)((const char*)Ash[BUF] +                           \
              (wr * 128 + (MH) * 64 + i * 16 + frow) * 128 +                     \
              (((KS) * 64 + fq16) ^ rswz));                                      \
    __VA_ARGS__;                                                                 \
    __builtin_amdgcn_s_setprio(1);                                               \
    _Pragma("unroll")                                                            \
    for (int i = 0; i < 4; ++i)                                                  \
      _Pragma("unroll")                                                          \
      for (int j = 0; j < 3; ++j)                                                \
        acc[(MH) * 4 + i][j] = __builtin_amdgcn_mfma_f32_16x16x32_bf16(          \
            af[i], breg[j], acc[(MH) * 4 + i][j], 0, 0, 0);                      \
    __builtin_amdgcn_s_setprio(0);                                               \
    VMC                                                                          \
    BARR                                                                         \
  }

template<int EPI>
__global__ __launch_bounds__(512, 2)
void gemm8p(const unsigned short* __restrict__ A,
            const unsigned short* __restrict__ Bw,
            const float* __restrict__ bias,
            void* __restrict__ outp,
            const int* __restrict__ invp)
{
    __shared__ unsigned short Ash[2][BM * 64];   // 2 x 32 KB
    __shared__ unsigned short Bsh[2][BN * 64];   // 2 x 24 KB

    const int tid  = threadIdx.x;
    const int w    = tid >> 6;
    const int lane = tid & 63;
    const int wr = w >> 2, wc = w & 3;

    // bijective XCD swizzle over exactly 256 workgroups (32 per XCD)
    int bid = blockIdx.x;
    int nb  = (bid & 7) * 32 + (bid >> 3);
    const int tileM = nb >> 2, tileN = nb & 3;
    const int m0 = tileM * BM, n0 = tileN * BN;

    // ---- staging addressing (linear LDS dest + inverse-swizzled global src) ----
    const int sRow = lane >> 3;                    // 0..7 within an 8-row group
    const int swzc = ((lane & 7) * 16) ^ ((sRow & 7) << 4);   // byte col in 128B row
    const unsigned short* gA0 = A  + (size_t)(m0 + w * 32 + sRow) * DM + (swzc >> 1);
    const unsigned short* gB0 = Bw + (size_t)(n0 + w * 24 + sRow) * DM + (swzc >> 1);

    auto STAGE_A = [&](int buf, int kt) {
        #pragma unroll
        for (int j = 0; j < 4; ++j)
            gload_lds16(gA0 + (size_t)j * 8 * DM + kt * 64,
                        &Ash[buf][(w * 32 + j * 8) * 64]);
    };
    auto STAGE_B = [&](int buf, int kt) {
        #pragma unroll
        for (int j = 0; j < 3; ++j)
            gload_lds16(gB0 + (size_t)j * 8 * DM + kt * 64,
                        &Bsh[buf][(w * 24 + j * 8) * 64]);
    };

    // ---- fragment read addressing ----
    const int frow = lane & 15;
    const int fq16 = (lane >> 4) * 16;             // k-quarter byte offset
    const int rswz = (lane & 7) << 4;              // row-based XOR (row&7 == lane&7)

    f32x4 acc[8][3] = {};
    short8 breg[3];

    // ---- prologue: A(0),B(0) -> buf0 ; B(1) -> buf1 ----
    STAGE_A(0, 0);
    STAGE_B(0, 0);
    STAGE_B(1, 1);
    VM3          // A0,B0 landed (B1 may still be in flight)
    BARR

    for (int it = 0; it < NPAIR; ++it) {
        const int kt0 = 2 * it;
        const bool hn = (it + 1 < NPAIR);
        // ---- phases 1-4: K-tile kt0 from buf0 ----
        DO_PHASE(0, 0, 0, 1, NOVM, STAGE_A(1, kt0 + 1))         // ph1
        DO_PHASE(0, 1, 0, 0, NOVM, )                            // ph2
        DO_PHASE(0, 0, 1, 1, NOVM, )                            // ph3
        DO_PHASE(0, 1, 1, 0, VMSEL, if (hn) STAGE_B(0, kt0 + 2))// ph4
        // ---- phases 5-8: K-tile kt0+1 from buf1 ----
        DO_PHASE(1, 0, 0, 1, NOVM, if (hn) STAGE_A(0, kt0 + 2)) // ph5
        DO_PHASE(1, 1, 0, 0, NOVM, )                            // ph6
        DO_PHASE(1, 0, 1, 1, NOVM, )                            // ph7
        DO_PHASE(1, 1, 1, 0, VMSEL, if (hn) STAGE_B(1, kt0 + 3))// ph8
    }

    // ---- epilogue ----
    const int crow = (lane >> 4) * 4;
    const int ccol = lane & 15;
    const int nbase = n0 + wc * 48;

    float bv[3];
    #pragma unroll
    for (int j = 0; j < 3; ++j) bv[j] = bias[nbase + j * 16 + ccol];

    if (EPI == 2) {
        float* O = (float*)outp;
        #pragma unroll
        for (int mi = 0; mi < 8; ++mi) {
            #pragma unroll
            for (int r = 0; r < 4; ++r) {
                int m = m0 + wr * 128 + mi * 16 + crow + r;
                int mo = (m & ~255) | invp[m];
                float* orow = O + (size_t)mo * DM + nbase + ccol;
                #pragma unroll
                for (int j = 0; j < 3; ++j)
                    orow[j * 16] = acc[mi][j][r] + bv[j];
            }
        }
    } else {
        unsigned short* O = (unsigned short*)outp;
        #pragma unroll
        for (int mi = 0; mi < 8; ++mi) {
            #pragma unroll
            for (int r = 0; r < 4; ++r) {
                int m = m0 + wr * 128 + mi * 16 + crow + r;
                unsigned short* orow = O + (size_t)m * DM + nbase + ccol;
                #pragma unroll
                for (int j = 0; j < 3; ++j) {
                    float v = acc[mi][j][r] + bv[j];
                    if (EPI == 0) v = fmaxf(v, 0.0f);
                    orow[j * 16] = f2bf(v);
                }
            }
        }
    }
}

// ---------------- BN stage 1: per-block partial sums over 128 rows ----------------
__global__ __launch_bounds__(256)
void bn_reduce1(const unsigned short* __restrict__ h, float* __restrict__ part)
{
    const int t = threadIdx.x, blk = blockIdx.x;   // 128 blocks
    const unsigned short* p = h + (size_t)blk * 128 * DM;
    float s0 = 0.f, s1 = 0.f, s2 = 0.f, q0 = 0.f, q1 = 0.f, q2 = 0.f;
    for (int r = 0; r < 128; ++r) {
        float v0 = bf2f(p[r * DM + t]);
        float v1 = bf2f(p[r * DM + t + 256]);
        float v2 = bf2f(p[r * DM + t + 512]);
        s0 += v0; q0 += v0 * v0;
        s1 += v1; q1 += v1 * v1;
        s2 += v2; q2 += v2 * v2;
    }
    float* dst = part + blk * (2 * DM);
    dst[t] = s0; dst[t + 256] = s1; dst[t + 512] = s2;
    dst[DM + t] = q0; dst[DM + t + 256] = q1; dst[DM + t + 512] = q2;
}

// ---------------- BN stage 2: finalize scale/shift ----------------
__global__ void bn_stats(const float* __restrict__ part, const float* __restrict__ gamma,
                         const float* __restrict__ beta, float* __restrict__ ss)
{
    int c = blockIdx.x * 256 + threadIdx.x;   // 768
    float s = 0.f, q = 0.f;
    for (int b = 0; b < 128; ++b) {
        s += part[b * 2 * DM + c];
        q += part[b * 2 * DM + DM + c];
    }
    float mu  = s * (1.0f / 16384.0f);
    float var = q * (1.0f / 16384.0f) - mu * mu;
    float scale = rsqrtf(var + 1e-5f) * gamma[c];
    ss[c] = scale;
    ss[DM + c] = beta[c] - mu * scale;
}

// ---------------- BN apply (+optional pos-emb + second relu) ----------------
template<int POS>
__global__ __launch_bounds__(256)
void bn_apply(const unsigned short* __restrict__ hin, const float* __restrict__ ss,
              const float* __restrict__ pos, unsigned short* __restrict__ hout)
{
    __shared__ float sc[DM], sh[DM];
    const int t = threadIdx.x;
    #pragma unroll
    for (int i = 0; i < 3; ++i) {
        sc[t + i * 256] = ss[t + i * 256];
        sh[t + i * 256] = ss[DM + t + i * 256];
    }
    __syncthreads();

    int g = blockIdx.x * 256 + t;           // 2,097,152... (16384*96) vec8 groups
    int row = g / 96;
    int c0 = (g - row * 96) * 8;
    const short8 v = *(const short8*)(hin + (size_t)row * DM + c0);
    short8 o;
    #pragma unroll
    for (int e = 0; e < 8; ++e) {
        float xv = bf2f((unsigned short)v[e]);
        float y = fmaxf(xv * sc[c0 + e] + sh[c0 + e], 0.0f);
        if (POS) y = fmaxf(y + pos[(row & 255) * DM + c0 + e], 0.0f);
        o[e] = (short)f2bf(y);
    }
    *(short8*)(hout + (size_t)row * DM + c0) = o;
}

extern "C" void kernel_launch(void* const* d_in, const int* in_sizes, int n_in,
                              void* d_out, int out_size, void* d_ws, size_t ws_size,
                              hipStream_t stream)
{
    (void)in_sizes; (void)n_in; (void)out_size; (void)ws_size;

    const float* x       = (const float*)d_in[0];
    const float* conv0_w = (const float*)d_in[1];
    const float* conv0_b = (const float*)d_in[2];
    const float* w1      = (const float*)d_in[3];
    const float* b1      = (const float*)d_in[4];
    const float* gamma   = (const float*)d_in[5];
    const float* beta    = (const float*)d_in[6];
    const float* pos     = (const float*)d_in[7];
    const float* mixer_w = (const float*)d_in[8];
    const float* mixer_b = (const float*)d_in[9];
    const int*   perm    = (const int*)d_in[10];

    // workspace layout (~58 MB)
    unsigned short* actA = (unsigned short*)d_ws;               // 16384*768 bf16
    unsigned short* actB = actA + (size_t)M_TOT * DM;           // 16384*768 bf16
    unsigned short* wA   = actB + (size_t)M_TOT * DM;           // 768*768
    unsigned short* wD   = wA + DM * DM;                        // 3*768*768
    unsigned short* wM   = wD + 3 * DM * DM;                    // 768*768
    float* part = (float*)(wM + DM * DM);                       // 128*2*768
    float* ss   = part + 128 * 2 * DM;                          // 2*768
    int*   invp = (int*)(ss + 2 * DM);                          // 16384

    cvt_bf16<<<576, 256, 0, stream>>>(conv0_w, wA, 147456);
    cvt_bf16<<<1728, 256, 0, stream>>>(w1, wD, 442368);
    cvt_bf16<<<576, 256, 0, stream>>>(mixer_w, wM, 147456);
    build_invperm<<<64, 256, 0, stream>>>(perm, invp);
    im2col<<<12288, 256, 0, stream>>>(x, actA);

    // patch embed: relu(patches @ conv0_w^T + b)
    gemm8p<0><<<256, 512, 0, stream>>>(actA, wA, conv0_b, actB, nullptr);

    for (int d = 0; d < 3; ++d) {
        gemm8p<1><<<256, 512, 0, stream>>>(actB, wD + (size_t)d * DM * DM, b1 + d * DM, actA, nullptr);
        bn_reduce1<<<128, 256, 0, stream>>>(actA, part);
        bn_stats<<<3, 256, 0, stream>>>(part, gamma + d * DM, beta + d * DM, ss);
        if (d < 2) bn_apply<0><<<6144, 256, 0, stream>>>(actA, ss, pos, actB);
        else       bn_apply<1><<<6144, 256, 0, stream>>>(actA, ss, pos, actB);
    }

    // mixer + per-sample permutation scatter to fp32 output
    gemm8p<2><<<256, 512, 0, stream>>>(actB, wM, mixer_b, d_out, invp);
}

// Round 3
// 228.671 us; speedup vs baseline: 1.2845x; 1.0398x over previous
//
#include <hip/hip_runtime.h>
#include <hip/hip_bf16.h>
#include <stdint.h>

#define M_TOT 16384     // B*P = 64*256
#define DM 768
#define BM 256
#define BN 192
#define NKT3 12         // K / 64
#define QOFF (128 * DM) // sumsq offset in bnpart

typedef __attribute__((ext_vector_type(4))) float f32x4;
typedef __attribute__((ext_vector_type(8))) short short8;
typedef __attribute__((ext_vector_type(4))) unsigned short ushort4v;

__device__ __forceinline__ unsigned short f2bf(float f) {
    union { float f; unsigned u; } v; v.f = f;
    unsigned r = v.u + 0x7fffu + ((v.u >> 16) & 1u);
    return (unsigned short)(r >> 16);
}
__device__ __forceinline__ float bf2f(unsigned short h) {
    union { unsigned u; float f; } v; v.u = ((unsigned)h) << 16;
    return v.f;
}

__device__ __forceinline__ void gload_lds16(const unsigned short* g, unsigned short* l) {
    __builtin_amdgcn_global_load_lds(
        (const __attribute__((address_space(1))) void*)g,
        (__attribute__((address_space(3))) void*)l, 16, 0, 0);
}

// ---------------- prep: all weight cvt + inverse permutation in ONE launch ----------------
__global__ __launch_bounds__(256)
void prep(const float* __restrict__ cw, const float* __restrict__ w1,
          const float* __restrict__ mw, const int* __restrict__ perm,
          unsigned short* __restrict__ wA, unsigned short* __restrict__ wD,
          unsigned short* __restrict__ wM, int* __restrict__ invp)
{
    int b = blockIdx.x;
    if (b < 2880) {
        int i = b * 256 + threadIdx.x;          // 737280 vec4 groups total
        const float* src; unsigned short* dst; int off;
        if (i < 147456)              { src = cw; dst = wA; off = i; }
        else if (i < 147456+442368)  { src = w1; dst = wD; off = i - 147456; }
        else                         { src = mw; dst = wM; off = i - 589824; }
        f32x4 v = ((const f32x4*)src)[off];
        ushort4v o;
        o.x = f2bf(v.x); o.y = f2bf(v.y); o.z = f2bf(v.z); o.w = f2bf(v.w);
        ((ushort4v*)dst)[off] = o;
    } else {
        int i = (b - 2880) * 256 + threadIdx.x;  // 16384
        int bb = i >> 8;
        invp[(bb << 8) + perm[i]] = i & 255;
    }
}

// ---------------- im2col: x[B,3,256,256] -> patches[16384,768] bf16 ----------------
__global__ __launch_bounds__(256)
void im2col(const float* __restrict__ x, unsigned short* __restrict__ patches)
{
    int t = blockIdx.x * 256 + threadIdx.x;     // 3,145,728 total (4 floats each)
    int bp = t / 192;
    int q  = t - bp * 192;
    int c   = q >> 6;
    int kh  = (q >> 2) & 15;
    int kw0 = (q & 3) << 2;
    int b = bp >> 8, p = bp & 255;
    int ph = p >> 4, pw = p & 15;
    const float* src = x + ((((size_t)b * 3 + c) * 256 + ph * 16 + kh) * 256 + pw * 16 + kw0);
    f32x4 v = *(const f32x4*)src;
    ushort4v o;
    o.x = f2bf(v.x); o.y = f2bf(v.y); o.z = f2bf(v.z); o.w = f2bf(v.w);
    *(ushort4v*)(patches + (size_t)bp * DM + (q << 2)) = o;
}

// =====================================================================
// GEMM: out[M,768] = A[M,768] * Bw[768,768]^T + bias
// BM=256 x BN=192, BK=64, 8 waves (2M x 4N), wave tile 128x48.
// 3-deep A buffer (stage 2 K-tiles ahead), 2-deep B, T2 swizzle,
// counted vmcnt(4) once per K-tile, T5 setprio.
// EPI 0: relu->bf16 ; EPI 1: ->bf16 + BN column partials ; EPI 2: perm-scatter->f32
// =====================================================================
#define VM4  asm volatile("s_waitcnt vmcnt(4)" ::: "memory");
#define VM0  asm volatile("s_waitcnt vmcnt(0)" ::: "memory");
#define BARR asm volatile("s_barrier" ::: "memory");
#define NOVM

#define DO_PHASE(AB, BB, MH, KS, LOADB, VMC, ...)                                \
  {                                                                              \
    if (LOADB) {                                                                 \
      _Pragma("unroll")                                                          \
      for (int j = 0; j < 3; ++j)                                                \
        breg[j] = *(const short8*)((const char*)Bb[BB] +                         \
                  (wc * 48 + j * 16 + frow) * 128 + (((KS) * 64 + fq16) ^ rswz));\
    }                                                                            \
    short8 af[4];                                                                \
    _Pragma("unroll")                                                            \
    for (int i = 0; i < 4; ++i)                                                  \
      af[i] = *(const short8*)((const char*)Aa[AB] +                             \
              (wr * 128 + (MH) * 64 + i * 16 + frow) * 128 +                     \
              (((KS) * 64 + fq16) ^ rswz));                                      \
    __VA_ARGS__;                                                                 \
    __builtin_amdgcn_s_setprio(1);                                               \
    _Pragma("unroll")                                                            \
    for (int i = 0; i < 4; ++i)                                                  \
      _Pragma("unroll")                                                          \
      for (int j = 0; j < 3; ++j)                                                \
        acc[(MH) * 4 + i][j] = __builtin_amdgcn_mfma_f32_16x16x32_bf16(          \
            af[i], breg[j], acc[(MH) * 4 + i][j], 0, 0, 0);                      \
    __builtin_amdgcn_s_setprio(0);                                               \
    VMC                                                                          \
    BARR                                                                         \
  }

template<int EPI>
__global__ __launch_bounds__(512, 2)
void gemm8p(const unsigned short* __restrict__ A,
            const unsigned short* __restrict__ Bw,
            const float* __restrict__ bias,
            void* __restrict__ outp,
            const int* __restrict__ invp,
            float* __restrict__ bnpart)
{
    __shared__ unsigned short Aa[3][BM * 64];   // 3 x 32 KB
    __shared__ unsigned short Bb[2][BN * 64];   // 2 x 24 KB  (total 144 KB)

    const int tid  = threadIdx.x;
    const int w    = tid >> 6;
    const int lane = tid & 63;
    const int wr = w >> 2, wc = w & 3;

    // bijective XCD swizzle over exactly 256 workgroups (32 per XCD)
    int bid = blockIdx.x;
    int nb  = (bid & 7) * 32 + (bid >> 3);
    const int tileM = nb >> 2, tileN = nb & 3;
    const int m0 = tileM * BM, n0 = tileN * BN;

    // ---- staging addressing (linear LDS dest + inverse-swizzled global src) ----
    const int sRow = lane >> 3;
    const int swzc = ((lane & 7) * 16) ^ ((sRow & 7) << 4);
    const unsigned short* gA0 = A  + (size_t)(m0 + w * 32 + sRow) * DM + (swzc >> 1);
    const unsigned short* gB0 = Bw + (size_t)(n0 + w * 24 + sRow) * DM + (swzc >> 1);

    auto STAGE_A = [&](int buf, int kt) {
        #pragma unroll
        for (int j = 0; j < 4; ++j)
            gload_lds16(gA0 + (size_t)j * 8 * DM + kt * 64,
                        &Aa[buf][(w * 32 + j * 8) * 64]);
    };
    auto STAGE_B = [&](int buf, int kt) {
        #pragma unroll
        for (int j = 0; j < 3; ++j)
            gload_lds16(gB0 + (size_t)j * 8 * DM + kt * 64,
                        &Bb[buf][(w * 24 + j * 8) * 64]);
    };

    const int frow = lane & 15;
    const int fq16 = (lane >> 4) * 16;
    const int rswz = (lane & 7) << 4;

    f32x4 acc[8][3] = {};
    short8 breg[3];

    // ---- prologue: A(0)->a0, B(0)->b0, A(1)->a1 ----
    STAGE_A(0, 0);
    STAGE_B(0, 0);
    STAGE_A(1, 1);
    VM4            // A(0), B(0) landed; A(1) in flight
    BARR

    #pragma unroll
    for (int kt = 0; kt < NKT3; ++kt) {
        const int ab = kt % 3, bb = kt & 1;
        // ph1: stage B(kt+1); compute MH=0, KS=0
        DO_PHASE(ab, bb, 0, 0, 1, NOVM, if (kt < 11) STAGE_B((kt + 1) & 1, kt + 1))
        // ph2: stage A(kt+2); compute MH=1, KS=0
        DO_PHASE(ab, bb, 1, 0, 0, NOVM, if (kt < 10) STAGE_A((kt + 2) % 3, kt + 2))
        // ph3: compute MH=0, KS=1
        DO_PHASE(ab, bb, 0, 1, 1, NOVM, )
        // ph4: compute MH=1, KS=1 + counted wait
        if (kt < 10)       { DO_PHASE(ab, bb, 1, 1, 0, VM4, ) }
        else if (kt == 10) { DO_PHASE(ab, bb, 1, 1, 0, VM0, ) }
        else               { DO_PHASE(ab, bb, 1, 1, 0, NOVM, ) }
    }

    // ---- epilogue ----
    const int crow = (lane >> 4) * 4;
    const int ccol = lane & 15;
    const int nbase = n0 + wc * 48;

    float bv[3];
    #pragma unroll
    for (int j = 0; j < 3; ++j) bv[j] = bias[nbase + j * 16 + ccol];

    if (EPI == 2) {
        float* O = (float*)outp;
        #pragma unroll
        for (int mi = 0; mi < 8; ++mi) {
            #pragma unroll
            for (int r = 0; r < 4; ++r) {
                int m = m0 + wr * 128 + mi * 16 + crow + r;
                int mo = (m & ~255) | invp[m];
                float* orow = O + (size_t)mo * DM + nbase + ccol;
                #pragma unroll
                for (int j = 0; j < 3; ++j)
                    orow[j * 16] = acc[mi][j][r] + bv[j];
            }
        }
    } else {
        unsigned short* O = (unsigned short*)outp;
        #pragma unroll
        for (int mi = 0; mi < 8; ++mi) {
            #pragma unroll
            for (int r = 0; r < 4; ++r) {
                int m = m0 + wr * 128 + mi * 16 + crow + r;
                unsigned short* orow = O + (size_t)m * DM + nbase + ccol;
                #pragma unroll
                for (int j = 0; j < 3; ++j) {
                    float v = acc[mi][j][r] + bv[j];
                    if (EPI == 0) v = fmaxf(v, 0.0f);
                    orow[j * 16] = f2bf(v);
                }
            }
        }
    }

    if (EPI == 1) {
        // deterministic BN column partials: this wave covers 128 rows x 48 cols
        #pragma unroll
        for (int j = 0; j < 3; ++j) {
            float s = 0.f, q = 0.f;
            #pragma unroll
            for (int mi = 0; mi < 8; ++mi)
                #pragma unroll
                for (int r = 0; r < 4; ++r) {
                    float v = acc[mi][j][r] + bv[j];
                    s += v; q += v * v;
                }
            s += __shfl_xor(s, 16); s += __shfl_xor(s, 32);
            q += __shfl_xor(q, 16); q += __shfl_xor(q, 32);
            if (lane < 16) {
                int c = nbase + j * 16 + lane;
                bnpart[(tileM * 2 + wr) * DM + c] = s;
                bnpart[QOFF + (tileM * 2 + wr) * DM + c] = q;
            }
        }
    }
}

// ---------------- BN finalize: reduce 128 partials -> scale/shift ----------------
__global__ void bn_stats(const float* __restrict__ part, const float* __restrict__ gamma,
                         const float* __restrict__ beta, float* __restrict__ ss)
{
    int c = blockIdx.x * 256 + threadIdx.x;   // 768
    float s = 0.f, q = 0.f;
    #pragma unroll 4
    for (int b = 0; b < 128; ++b) {
        s += part[b * DM + c];
        q += part[QOFF + b * DM + c];
    }
    float mu  = s * (1.0f / 16384.0f);
    float var = q * (1.0f / 16384.0f) - mu * mu;
    float scale = rsqrtf(var + 1e-5f) * gamma[c];
    ss[c] = scale;
    ss[DM + c] = beta[c] - mu * scale;
}

// ---------------- BN apply (+optional pos-emb + second relu) ----------------
template<int POS>
__global__ __launch_bounds__(256)
void bn_apply(const unsigned short* __restrict__ hin, const float* __restrict__ ss,
              const float* __restrict__ pos, unsigned short* __restrict__ hout)
{
    __shared__ float sc[DM], sh[DM];
    const int t = threadIdx.x;
    #pragma unroll
    for (int i = 0; i < 3; ++i) {
        sc[t + i * 256] = ss[t + i * 256];
        sh[t + i * 256] = ss[DM + t + i * 256];
    }
    __syncthreads();

    int g = blockIdx.x * 256 + t;
    int row = g / 96;
    int c0 = (g - row * 96) * 8;
    const short8 v = *(const short8*)(hin + (size_t)row * DM + c0);
    short8 o;
    #pragma unroll
    for (int e = 0; e < 8; ++e) {
        float xv = bf2f((unsigned short)v[e]);
        float y = fmaxf(xv * sc[c0 + e] + sh[c0 + e], 0.0f);
        if (POS) y = fmaxf(y + pos[(row & 255) * DM + c0 + e], 0.0f);
        o[e] = (short)f2bf(y);
    }
    *(short8*)(hout + (size_t)row * DM + c0) = o;
}

extern "C" void kernel_launch(void* const* d_in, const int* in_sizes, int n_in,
                              void* d_out, int out_size, void* d_ws, size_t ws_size,
                              hipStream_t stream)
{
    (void)in_sizes; (void)n_in; (void)out_size; (void)ws_size;

    const float* x       = (const float*)d_in[0];
    const float* conv0_w = (const float*)d_in[1];
    const float* conv0_b = (const float*)d_in[2];
    const float* w1      = (const float*)d_in[3];
    const float* b1      = (const float*)d_in[4];
    const float* gamma   = (const float*)d_in[5];
    const float* beta    = (const float*)d_in[6];
    const float* pos     = (const float*)d_in[7];
    const float* mixer_w = (const float*)d_in[8];
    const float* mixer_b = (const float*)d_in[9];
    const int*   perm    = (const int*)d_in[10];

    // workspace layout (~54 MB)
    unsigned short* actA = (unsigned short*)d_ws;               // 16384*768 bf16
    unsigned short* actB = actA + (size_t)M_TOT * DM;           // 16384*768 bf16
    unsigned short* wA   = actB + (size_t)M_TOT * DM;           // 768*768
    unsigned short* wD   = wA + DM * DM;                        // 3*768*768
    unsigned short* wM   = wD + 3 * DM * DM;                    // 768*768
    float* bnpart = (float*)(wM + DM * DM);                     // 2*128*768
    float* ss     = bnpart + 2 * 128 * DM;                      // 2*768
    int*   invp   = (int*)(ss + 2 * DM);                        // 16384

    prep<<<2944, 256, 0, stream>>>(conv0_w, w1, mixer_w, perm, wA, wD, wM, invp);
    im2col<<<12288, 256, 0, stream>>>(x, actA);

    // patch embed: relu(patches @ conv0_w^T + b)
    gemm8p<0><<<256, 512, 0, stream>>>(actA, wA, conv0_b, actB, nullptr, nullptr);

    for (int d = 0; d < 3; ++d) {
        gemm8p<1><<<256, 512, 0, stream>>>(actB, wD + (size_t)d * DM * DM, b1 + d * DM,
                                           actA, nullptr, bnpart);
        bn_stats<<<3, 256, 0, stream>>>(bnpart, gamma + d * DM, beta + d * DM, ss);
        if (d < 2) bn_apply<0><<<6144, 256, 0, stream>>>(actA, ss, pos, actB);
        else       bn_apply<1><<<6144, 256, 0, stream>>>(actA, ss, pos, actB);
    }

    // mixer + per-sample permutation scatter to fp32 output
    gemm8p<2><<<256, 512, 0, stream>>>(actB, wM, mixer_b, d_out, invp, nullptr);
}